// Round 1
// baseline (3180.838 us; speedup 1.0000x reference)
//
#include <hip/hip_runtime.h>

// AnchorStore: KL-argmin 1-NN classifier.
//   score[b,k] = sum_d A[k,d]*log(A[k,d]) - sum_d A[k,d]*log(Q[b,d])   (D* kl, argmin-equivalent)
//   out[b] = label[argmin_k score[b,k]]
// K=2048 anchors, D=50257, B=256 queries.
// Pass 1: grid (K/64, S) blocks; each computes partial cross sums over a D-chunk
//         for its 64 anchors x all 256 queries, plus partial self sums.
// Pass 2: reduce partials over chunks, argmin over k per query, gather label.

constexpr int K  = 2048;
constexpr int D  = 50257;
constexpr int B  = 256;
constexpr int TK = 64;   // anchors per block
constexpr int DK = 32;   // D-depth per LDS tile
constexpr int LSTR = 34; // LDS row stride in floats (even -> b64-aligned, conflict-free)

__global__ __launch_bounds__(256)
void kl_partial_kernel(const float* __restrict__ query,   // [B][D]
                       const float* __restrict__ anchor,  // [K][D]
                       float* __restrict__ crossp,        // [S][B][K]
                       float* __restrict__ selfp,         // [S][K]
                       int dc)                            // D-chunk length
{
    const int t  = threadIdx.x;
    const int tx = t & 31;
    const int ty = t >> 5;                 // 0..7
    const int k0 = blockIdx.x * TK;
    const int s  = blockIdx.y;
    const int d0 = s * dc;
    const int dend = min(d0 + dc, D);

    __shared__ __align__(16) float As[TK * LSTR];   // 8.5 KB
    __shared__ __align__(16) float Qs[B  * LSTR];   // 34 KB

    // per-thread output mapping: k = k0 + (tx&7) + 8*i,  b = (ty*4 + (tx>>3)) + 32*j
    const int klane = tx & 7;
    const int blane = ty * 4 + (tx >> 3);

    float acc[8][8];
#pragma unroll
    for (int i = 0; i < 8; ++i)
#pragma unroll
        for (int j = 0; j < 8; ++j) acc[i][j] = 0.f;

    float selfacc[8];   // slot m accumulates row (m*8 + ty)
#pragma unroll
    for (int m = 0; m < 8; ++m) selfacc[m] = 0.f;

    for (int dt = d0; dt < dend; dt += DK) {
        __syncthreads();   // protect LDS from previous iteration's readers
        // ---- stage A tile (64 x 32), fuse self-term accumulation ----
#pragma unroll
        for (int m = 0; m < 8; ++m) {
            const int c = tx;              // 0..31 (t & 31)
            const int r = m * 8 + ty;      // 0..63
            const int d = dt + c;
            float a = 0.f;
            if (d < dend) {
                a = anchor[(size_t)(k0 + r) * D + d];
                selfacc[m] = fmaf(a, __logf(a), selfacc[m]);
            }
            As[r * LSTR + c] = a;
        }
        // ---- stage log(Q) tile (256 x 32), log computed on the fly ----
#pragma unroll
        for (int m = 0; m < 32; ++m) {
            const int c = tx;
            const int r = m * 8 + ty;      // 0..255
            const int d = dt + c;
            float q = 0.f;
            if (d < dend) q = __logf(query[(size_t)r * D + d]);
            Qs[r * LSTR + c] = q;
        }
        __syncthreads();
        // ---- 8x8 register-tile FMA over 32-deep chunk ----
#pragma unroll
        for (int dd = 0; dd < DK; dd += 2) {
            float2 a2[8], q2[8];
#pragma unroll
            for (int i = 0; i < 8; ++i)
                a2[i] = *reinterpret_cast<const float2*>(&As[(klane + 8 * i) * LSTR + dd]);
#pragma unroll
            for (int j = 0; j < 8; ++j)
                q2[j] = *reinterpret_cast<const float2*>(&Qs[(blane + 32 * j) * LSTR + dd]);
#pragma unroll
            for (int i = 0; i < 8; ++i)
#pragma unroll
                for (int j = 0; j < 8; ++j) {
                    acc[i][j] = fmaf(a2[i].x, q2[j].x, acc[i][j]);
                    acc[i][j] = fmaf(a2[i].y, q2[j].y, acc[i][j]);
                }
        }
    }

    // ---- write cross partials [s][b][k] ----
#pragma unroll
    for (int i = 0; i < 8; ++i)
#pragma unroll
        for (int j = 0; j < 8; ++j) {
            const int k = k0 + klane + 8 * i;
            const int b = blane + 32 * j;
            crossp[((size_t)s * B + b) * K + k] = acc[i][j];
        }

    // ---- reduce self partials: row r gets 32 thread contributions ----
    __syncthreads();
    float* red = Qs;   // reuse as scratch (needs 64*33 floats)
#pragma unroll
    for (int m = 0; m < 8; ++m)
        red[(m * 8 + ty) * 33 + tx] = selfacc[m];
    __syncthreads();
    if (t < TK) {
        float ssum = 0.f;
        for (int i = 0; i < 32; ++i) ssum += red[t * 33 + i];
        selfp[(size_t)s * K + k0 + t] = ssum;
    }
}

__global__ __launch_bounds__(256)
void argmin_label_kernel(const float* __restrict__ crossp,  // [S][B][K]
                         const float* __restrict__ selfp,   // [S][K]
                         const int* __restrict__ label,     // [K]
                         int* __restrict__ out,             // [B]
                         int s_chunks)
{
    const int b = blockIdx.x;
    const int t = threadIdx.x;
    float best = 3.4e38f;
    int bestk = 0;
    for (int k = t; k < K; k += 256) {
        float sv = 0.f, cv = 0.f;
        for (int ss = 0; ss < s_chunks; ++ss) sv += selfp[(size_t)ss * K + k];
        for (int ss = 0; ss < s_chunks; ++ss) cv += crossp[((size_t)ss * B + b) * K + k];
        const float score = sv - cv;   // = D * kl[b,k]
        if (score < best) { best = score; bestk = k; }   // k ascending -> first-min kept
    }
    __shared__ float vals[256];
    __shared__ int   idxs[256];
    vals[t] = best; idxs[t] = bestk;
    __syncthreads();
    for (int off = 128; off > 0; off >>= 1) {
        if (t < off) {
            const float v2 = vals[t + off];
            const int   i2 = idxs[t + off];
            if (v2 < vals[t] || (v2 == vals[t] && i2 < idxs[t])) { vals[t] = v2; idxs[t] = i2; }
        }
        __syncthreads();
    }
    if (t == 0) out[b] = label[idxs[0]];
}

extern "C" void kernel_launch(void* const* d_in, const int* in_sizes, int n_in,
                              void* d_out, int out_size, void* d_ws, size_t ws_size,
                              hipStream_t stream)
{
    const float* query  = (const float*)d_in[0];   // [B*D]
    const float* anchor = (const float*)d_in[1];   // [K*D]
    const int*   label  = (const int*)d_in[2];     // [K] (int32 assumed)
    int* out = (int*)d_out;

    // choose # of D-chunks to fit workspace: needs s*(B*K + K) floats
    const size_t per_s = (size_t)B * K + K;
    int s_chunks = (int)((ws_size / sizeof(float)) / per_s);
    if (s_chunks > 16) s_chunks = 16;
    if (s_chunks < 1)  s_chunks = 1;
    // chunk length: multiple of DK covering D
    int dc = ((D + s_chunks - 1) / s_chunks + DK - 1) & ~(DK - 1);

    float* crossp = (float*)d_ws;
    float* selfp  = crossp + (size_t)s_chunks * B * K;

    kl_partial_kernel<<<dim3(K / TK, s_chunks), 256, 0, stream>>>(query, anchor, crossp, selfp, dc);
    argmin_label_kernel<<<B, 256, 0, stream>>>(crossp, selfp, label, out, s_chunks);
}

// Round 2
// 641.671 us; speedup vs baseline: 4.9571x; 4.9571x over previous
//
#include <hip/hip_runtime.h>

// AnchorStore: KL-argmin 1-NN.
//   score[b,k] = sum_d A[k,d]*log A[k,d]  -  sum_d A[k,d]*log Q[b,d]
//   out[b] = label[argmin_k score[b,k]],  K=2048, D=50257, B=256.
// Plan: bf16 MFMA GEMM for approximate cross-term (fp32 atomic accumulation
// over D-chunks), exact fp32 self-term fused into A staging, per-query top-8
// candidates, exact f64-accum rescore of candidates, label gather.

constexpr int K   = 2048;
constexpr int D   = 50257;
constexpr int B   = 256;
constexpr int BM  = 128;
constexpr int BN  = 128;
constexpr int BKD = 64;
constexpr int SCH = 24;      // D-chunks -> grid 16*2*24 = 768 blocks
constexpr int DP  = 50320;   // padded log(Q) row stride (mult of 8, >= D+63)

typedef __attribute__((ext_vector_type(8))) short bf16x8;
typedef __attribute__((ext_vector_type(4))) float f32x4;
typedef __attribute__((ext_vector_type(8))) unsigned short u16x8;

__device__ inline unsigned short f2bf_rne(float f) {
    union { float f; unsigned u; } v; v.f = f;
    unsigned r = v.u + 0x7FFFu + ((v.u >> 16) & 1u);
    return (unsigned short)(r >> 16);
}

// ---------------- pre-pass: lq[b][dp] = bf16(log(q[b][dp])), zero-padded ----
__global__ __launch_bounds__(256)
void lq_kernel(const float* __restrict__ q, unsigned short* __restrict__ lq)
{
    const int stride = gridDim.x * blockDim.x;
    const int total  = B * (DP / 4);
    for (int c = blockIdx.x * blockDim.x + threadIdx.x; c < total; c += stride) {
        const int b   = c / (DP / 4);
        const int off = (c % (DP / 4)) * 4;
        ushort4 w;
        float v0 = (off + 0 < D) ? __logf(q[(size_t)b * D + off + 0]) : 0.f;
        float v1 = (off + 1 < D) ? __logf(q[(size_t)b * D + off + 1]) : 0.f;
        float v2 = (off + 2 < D) ? __logf(q[(size_t)b * D + off + 2]) : 0.f;
        float v3 = (off + 3 < D) ? __logf(q[(size_t)b * D + off + 3]) : 0.f;
        w.x = f2bf_rne(v0); w.y = f2bf_rne(v1); w.z = f2bf_rne(v2); w.w = f2bf_rne(v3);
        *reinterpret_cast<ushort4*>(&lq[(size_t)b * DP + off]) = w;
    }
}

// ---------------- main GEMM: cross[b][k] += A_tile . LQ_tile (bf16 MFMA) ----
template<bool USELQ>
__global__ __launch_bounds__(512, 4)
void gemm_kernel(const float* __restrict__ query,
                 const float* __restrict__ anchor,
                 const unsigned short* __restrict__ lq,
                 float* __restrict__ cross,     // [B][K] (atomic accum)
                 float* __restrict__ selftot,   // [K]    (atomic accum)
                 int dc)
{
    const int t    = threadIdx.x;
    const int k0   = blockIdx.x * BM;
    const int b0   = blockIdx.y * BN;
    const int d0   = blockIdx.z * dc;
    const int dend = min(d0 + dc, D);
    if (d0 >= dend) return;

    __shared__ __align__(16) unsigned short Al[BM * 64];  // 16 KB, swizzled
    __shared__ __align__(16) unsigned short Ql[BN * 64];  // 16 KB, swizzled

    // staging mapping: thread -> (row = t>>2, 16 cols at (t&3)*16)
    const int trow = t >> 2;
    const int tq   = t & 3;
    const int sw8  = (trow & 7) << 3;   // XOR swizzle in ushort units

    const float*          Arow  = anchor + (size_t)(k0 + trow) * D;
    const float*          Qrow  = query  + (size_t)(b0 + trow) * D;
    const unsigned short* LQrow = lq     + (size_t)(b0 + trow) * DP;

    // per-wave MFMA geometry: 8 waves in 2(m) x 4(n); wave tile 64x32
    const int w    = t >> 6;
    const int lane = t & 63;
    const int wm   = (w >> 2) * 64;
    const int wn   = (w & 3) * 32;
    const int lrow = lane & 15;
    const int kg   = lane >> 4;      // 0..3

    f32x4 acc[4][2];
#pragma unroll
    for (int mt = 0; mt < 4; ++mt)
#pragma unroll
        for (int nt = 0; nt < 2; ++nt)
#pragma unroll
            for (int i = 0; i < 4; ++i) acc[mt][nt][i] = 0.f;

    float selfacc = 0.f;
    const bool doself = (blockIdx.y == 0);

    float areg[16];
    u16x8 qreg[2];
    float qf32[16];

    auto load_step = [&](int dt) {
        const int dbase = dt + tq * 16;
#pragma unroll
        for (int jj = 0; jj < 16; ++jj) {
            const int d = dbase + jj;
            areg[jj] = (d < dend) ? Arow[d] : 0.f;
        }
        if constexpr (USELQ) {
            qreg[0] = *reinterpret_cast<const u16x8*>(&LQrow[dbase]);
            qreg[1] = *reinterpret_cast<const u16x8*>(&LQrow[dbase + 8]);
        } else {
#pragma unroll
            for (int jj = 0; jj < 16; ++jj) {
                const int d = dbase + jj;
                qf32[jj] = (d < dend) ? Qrow[d] : 1.f;   // log(1)=0
            }
        }
    };

    load_step(d0);

    for (int dt = d0; dt < dend; dt += BKD) {
        // ---- convert A -> bf16, fused exact self-term ----
        unsigned short abf[16];
#pragma unroll
        for (int jj = 0; jj < 16; ++jj) abf[jj] = f2bf_rne(areg[jj]);
        if (doself) {
#pragma unroll
            for (int jj = 0; jj < 16; ++jj)
                if (areg[jj] > 0.f) selfacc = fmaf(areg[jj], __logf(areg[jj]), selfacc);
        }
        u16x8 qb0, qb1;
        if constexpr (USELQ) {
            qb0 = qreg[0]; qb1 = qreg[1];
        } else {
#pragma unroll
            for (int j = 0; j < 8; ++j) qb0[j] = f2bf_rne(__logf(qf32[j]));
#pragma unroll
            for (int j = 0; j < 8; ++j) qb1[j] = f2bf_rne(__logf(qf32[8 + j]));
        }

        __syncthreads();   // previous iteration's MFMA readers done
        {
            unsigned short* a0 = &Al[trow * 64 + ((tq * 16)     ^ sw8)];
            unsigned short* a1 = &Al[trow * 64 + ((tq * 16 + 8) ^ sw8)];
            reinterpret_cast<ushort4*>(a0)[0] = ushort4{abf[0], abf[1], abf[2],  abf[3]};
            reinterpret_cast<ushort4*>(a0)[1] = ushort4{abf[4], abf[5], abf[6],  abf[7]};
            reinterpret_cast<ushort4*>(a1)[0] = ushort4{abf[8], abf[9], abf[10], abf[11]};
            reinterpret_cast<ushort4*>(a1)[1] = ushort4{abf[12], abf[13], abf[14], abf[15]};
            *reinterpret_cast<u16x8*>(&Ql[trow * 64 + ((tq * 16)     ^ sw8)]) = qb0;
            *reinterpret_cast<u16x8*>(&Ql[trow * 64 + ((tq * 16 + 8) ^ sw8)]) = qb1;
        }
        __syncthreads();

        if (dt + BKD < dend) load_step(dt + BKD);   // next loads in flight during MFMA

        // ---- MFMA over the 64-deep tile ----
#pragma unroll
        for (int half = 0; half < 2; ++half) {
            const int dd = half * 32;
            bf16x8 af[4], qf[2];
#pragma unroll
            for (int mt = 0; mt < 4; ++mt) {
                const int r = wm + mt * 16 + lrow;
                const int c = (dd + kg * 8) ^ ((r & 7) << 3);
                af[mt] = *reinterpret_cast<const bf16x8*>(&Al[r * 64 + c]);
            }
#pragma unroll
            for (int nt = 0; nt < 2; ++nt) {
                const int r = wn + nt * 16 + lrow;
                const int c = (dd + kg * 8) ^ ((r & 7) << 3);
                qf[nt] = *reinterpret_cast<const bf16x8*>(&Ql[r * 64 + c]);
            }
#pragma unroll
            for (int mt = 0; mt < 4; ++mt)
#pragma unroll
                for (int nt = 0; nt < 2; ++nt)
                    acc[mt][nt] = __builtin_amdgcn_mfma_f32_16x16x32_bf16(
                        af[mt], qf[nt], acc[mt][nt], 0, 0, 0);
        }
    }

    // ---- epilogue: accumulate cross partials (C/D: col=lane&15, row=(lane>>4)*4+i) ----
#pragma unroll
    for (int mt = 0; mt < 4; ++mt)
#pragma unroll
        for (int nt = 0; nt < 2; ++nt) {
            const int kb = k0 + wm + mt * 16 + kg * 4;
            const int bb = b0 + wn + nt * 16 + lrow;
            float* dst = &cross[(size_t)bb * K + kb];
#pragma unroll
            for (int i = 0; i < 4; ++i) atomicAdd(&dst[i], acc[mt][nt][i]);
        }
    if (doself) {
        float s = selfacc;
        s += __shfl_xor(s, 1);
        s += __shfl_xor(s, 2);
        if (tq == 0) atomicAdd(&selftot[k0 + trow], s);
    }
}

// ---------------- per-query top-8 candidates over approx scores ----------------
__global__ __launch_bounds__(256)
void topk_kernel(const float* __restrict__ cross, const float* __restrict__ selftot,
                 int* __restrict__ cand)
{
    const int b = blockIdx.x, t = threadIdx.x;
    float v[8];
#pragma unroll
    for (int i = 0; i < 8; ++i) {
        const int k = i * 256 + t;
        v[i] = selftot[k] - cross[(size_t)b * K + k];
    }
    __shared__ float sv[256];
    __shared__ int   si[256];
    for (int r = 0; r < 8; ++r) {
        float bv = 3.4e38f; int bk = K;
#pragma unroll
        for (int i = 0; i < 8; ++i) {
            const int k = i * 256 + t;
            if (v[i] < bv) { bv = v[i]; bk = k; }
        }
        sv[t] = bv; si[t] = bk;
        __syncthreads();
        for (int off = 128; off > 0; off >>= 1) {
            if (t < off) {
                if (sv[t + off] < sv[t] || (sv[t + off] == sv[t] && si[t + off] < si[t])) {
                    sv[t] = sv[t + off]; si[t] = si[t + off];
                }
            }
            __syncthreads();
        }
        const int kwin = si[0];
        if ((kwin & 255) == t) v[kwin >> 8] = 3.4e38f;
        if (t == 0) cand[b * 8 + r] = kwin;
        __syncthreads();
    }
}

// ---------------- exact rescore of candidates + label gather ----------------
__global__ __launch_bounds__(256)
void rescore_kernel(const float* __restrict__ query, const float* __restrict__ anchor,
                    const float* __restrict__ selftot, const int* __restrict__ cand,
                    const int* __restrict__ label, int* __restrict__ out)
{
    const int b = blockIdx.x, t = threadIdx.x;
    int ks[8];
#pragma unroll
    for (int c = 0; c < 8; ++c) ks[c] = cand[b * 8 + c];
    const float* qrow = query + (size_t)b * D;

    double acc[8];
#pragma unroll
    for (int c = 0; c < 8; ++c) acc[c] = 0.0;

    for (int d = t; d < D; d += 256) {
        const double lqv = (double)logf(qrow[d]);
#pragma unroll
        for (int c = 0; c < 8; ++c)
            acc[c] = fma((double)anchor[(size_t)ks[c] * D + d], lqv, acc[c]);
    }

    __shared__ double red[256];
    __shared__ double fin[8];
    for (int c = 0; c < 8; ++c) {
        red[t] = acc[c];
        __syncthreads();
        for (int off = 128; off > 0; off >>= 1) {
            if (t < off) red[t] += red[t + off];
            __syncthreads();
        }
        if (t == 0) fin[c] = red[0];
        __syncthreads();
    }

    if (t == 0) {
        float best = 3.4e38f; int bk = K;
#pragma unroll
        for (int c = 0; c < 8; ++c) {
            const float sc = selftot[ks[c]] - (float)fin[c];
            if (sc < best || (sc == best && ks[c] < bk)) { best = sc; bk = ks[c]; }
        }
        out[b] = label[bk];
    }
}

extern "C" void kernel_launch(void* const* d_in, const int* in_sizes, int n_in,
                              void* d_out, int out_size, void* d_ws, size_t ws_size,
                              hipStream_t stream)
{
    const float* query  = (const float*)d_in[0];   // [B*D]
    const float* anchor = (const float*)d_in[1];   // [K*D]
    const int*   label  = (const int*)d_in[2];     // [K]
    int* out = (int*)d_out;

    float* cross   = (float*)d_ws;                        // B*K
    float* selftot = cross + (size_t)B * K;               // K
    int*   cand    = (int*)(selftot + K);                 // B*8
    unsigned short* lq = (unsigned short*)(cand + B * 8); // B*DP

    const size_t need_lq = ((size_t)B * K + K + B * 8) * 4 + (size_t)B * DP * 2;
    const bool uselq = (ws_size >= need_lq);

    const int dc = (((D + SCH - 1) / SCH) + BKD - 1) / BKD * BKD;

    hipMemsetAsync(cross, 0, ((size_t)B * K + K) * sizeof(float), stream);
    if (uselq) {
        lq_kernel<<<1024, 256, 0, stream>>>(query, lq);
        gemm_kernel<true><<<dim3(K / BM, B / BN, SCH), 512, 0, stream>>>(
            query, anchor, lq, cross, selftot, dc);
    } else {
        gemm_kernel<false><<<dim3(K / BM, B / BN, SCH), 512, 0, stream>>>(
            query, anchor, lq, cross, selftot, dc);
    }
    topk_kernel<<<B, 256, 0, stream>>>(cross, selftot, cand);
    rescore_kernel<<<B, 256, 0, stream>>>(query, anchor, selftot, cand, label, out);
}

// Round 3
// 588.885 us; speedup vs baseline: 5.4015x; 1.0896x over previous
//
#include <hip/hip_runtime.h>

// AnchorStore: KL-argmin 1-NN.
//   score[b,k] = sum_d A[k,d]*log A[k,d]  -  sum_d A[k,d]*log Q[b,d]
//   out[b] = label[argmin_k score[b,k]],  K=2048, D=50257, B=256.
// bf16 MFMA GEMM (approx cross), exact fp32 self-term, top-4 candidates,
// fp64 rescore, label gather. A read once (BN=256); vector A loads via
// alignment-phase select (D odd); deterministic ws partials over D-chunks.

constexpr int K   = 2048;
constexpr int D   = 50257;
constexpr int B   = 256;
constexpr int BM  = 64;
constexpr int BN  = 256;
constexpr int BK  = 64;
constexpr int SCH = 32;      // D-chunks
constexpr int DP  = 50320;   // padded log(Q) row stride (mult of 8, >= D+63)
constexpr int NC  = 4;       // rescore candidates

typedef __attribute__((ext_vector_type(8))) short bf16x8;
typedef __attribute__((ext_vector_type(4))) float f32x4;
typedef __attribute__((ext_vector_type(8))) unsigned short u16x8;

__device__ inline unsigned short f2bf_rne(float f) {
    union { float f; unsigned u; } v; v.f = f;
    unsigned r = v.u + 0x7FFFu + ((v.u >> 16) & 1u);
    return (unsigned short)(r >> 16);
}

// ---------------- pre-pass: lq[b][dp] = bf16(log(q[b][dp])), zero-padded ----
__global__ __launch_bounds__(256)
void lq_kernel(const float* __restrict__ q, unsigned short* __restrict__ lq)
{
    const int stride = gridDim.x * blockDim.x;
    const int total  = B * (DP / 4);
    for (int c = blockIdx.x * blockDim.x + threadIdx.x; c < total; c += stride) {
        const int b   = c / (DP / 4);
        const int off = (c % (DP / 4)) * 4;
        ushort4 w;
        float v0 = (off + 0 < D) ? __logf(q[(size_t)b * D + off + 0]) : 0.f;
        float v1 = (off + 1 < D) ? __logf(q[(size_t)b * D + off + 1]) : 0.f;
        float v2 = (off + 2 < D) ? __logf(q[(size_t)b * D + off + 2]) : 0.f;
        float v3 = (off + 3 < D) ? __logf(q[(size_t)b * D + off + 3]) : 0.f;
        w.x = f2bf_rne(v0); w.y = f2bf_rne(v1); w.z = f2bf_rne(v2); w.w = f2bf_rne(v3);
        *reinterpret_cast<ushort4*>(&lq[(size_t)b * DP + off]) = w;
    }
}

// ---------------- main GEMM: cross[b][k] partials over D-chunks ----------------
template<bool WSP>
__global__ __launch_bounds__(512, 4)
void gemm_kernel(const float* __restrict__ anchor,
                 const unsigned short* __restrict__ lq,
                 float* __restrict__ outc,    // WSP: part[SCH][B][K]; else cross[B][K]
                 float* __restrict__ selfp,   // [SCH][K]
                 int dc)
{
    const int t    = threadIdx.x;
    const int k0   = blockIdx.x * BM;
    const int z    = blockIdx.y;
    const int d0   = z * dc;
    const int dend = min(d0 + dc, D);

    __shared__ __align__(16) unsigned short Al[BM * 64];  //  8 KB, swizzled
    __shared__ __align__(16) unsigned short Ql[BN * 64];  // 32 KB, swizzled

    // A staging: row = t>>3 (0..63), 8 cols at (t&7)*8
    const int rowA = t >> 3;
    const int tq8  = t & 7;
    const int ar   = k0 + rowA;
    const int swA  = (rowA & 7) << 3;
    const float* Arow = anchor + (size_t)ar * D;

    // Q staging: row = t>>1 (0..255), 32 cols at (t&1)*32
    const int rowQ = t >> 1;
    const int hq   = t & 1;
    const int swQ  = (rowQ & 7) << 3;
    const unsigned short* LQrow = lq + (size_t)rowQ * DP;

    // MFMA geometry: 8 waves in 2(m) x 4(n); wave tile 32x64
    const int w    = t >> 6;
    const int lane = t & 63;
    const int wm   = (w >> 2) * 32;
    const int wn   = (w & 3) * 64;
    const int lrow = lane & 15;
    const int kg   = lane >> 4;

    f32x4 acc[2][4];
#pragma unroll
    for (int mt = 0; mt < 2; ++mt)
#pragma unroll
        for (int nt = 0; nt < 4; ++nt)
#pragma unroll
            for (int i = 0; i < 4; ++i) acc[mt][nt][i] = 0.f;

    float selfacc = 0.f;

    float wf[12];
    int   ph = 0;
    u16x8 qreg[4];

    auto load_step = [&](int dt) {
        const int dbase = dt + tq8 * 8;
        if (dbase + 12 <= dend) {
            // vector path: 3 aligned float4 covering [g0-ph, g0-ph+12) ⊇ wanted 8
            const size_t g0 = (size_t)ar * D + dbase;
            ph = (int)(g0 & 3);
            const float4* wp = reinterpret_cast<const float4*>(anchor + (g0 - ph));
            const float4 w0 = wp[0], w1 = wp[1], w2 = wp[2];
            wf[0] = w0.x; wf[1]  = w0.y; wf[2]  = w0.z; wf[3]  = w0.w;
            wf[4] = w1.x; wf[5]  = w1.y; wf[6]  = w1.z; wf[7]  = w1.w;
            wf[8] = w2.x; wf[9]  = w2.y; wf[10] = w2.z; wf[11] = w2.w;
        } else {
            ph = 0;
#pragma unroll
            for (int j = 0; j < 8; ++j) {
                const int d = dbase + j;
                wf[j] = (d < dend) ? Arow[d] : 0.f;
            }
#pragma unroll
            for (int j = 8; j < 12; ++j) wf[j] = 0.f;
        }
        const int qb = dt + hq * 32;
#pragma unroll
        for (int g = 0; g < 4; ++g)
            qreg[g] = *reinterpret_cast<const u16x8*>(&LQrow[qb + 8 * g]);
    };

    load_step(d0);

    for (int dt = d0; dt < dend; dt += BK) {
        // ---- alignment-phase select (compile-time indices only) ----
        float s1[9], av[8];
#pragma unroll
        for (int j = 0; j < 9; ++j) s1[j] = (ph & 2) ? wf[j + 2] : wf[j];
#pragma unroll
        for (int j = 0; j < 8; ++j) av[j] = (ph & 1) ? s1[j + 1] : s1[j];

        unsigned short abf[8];
#pragma unroll
        for (int j = 0; j < 8; ++j) {
            if (av[j] > 0.f) selfacc = fmaf(av[j], __logf(av[j]), selfacc);
            abf[j] = f2bf_rne(av[j]);
        }

        __syncthreads();   // previous step's MFMA readers done
        {
            unsigned short* a0 = &Al[rowA * 64 + ((tq8 * 8) ^ swA)];
            reinterpret_cast<ushort4*>(a0)[0] = ushort4{abf[0], abf[1], abf[2], abf[3]};
            reinterpret_cast<ushort4*>(a0)[1] = ushort4{abf[4], abf[5], abf[6], abf[7]};
#pragma unroll
            for (int g = 0; g < 4; ++g)
                *reinterpret_cast<u16x8*>(&Ql[rowQ * 64 + ((hq * 32 + 8 * g) ^ swQ)]) = qreg[g];
        }
        __syncthreads();

        if (dt + BK < dend) load_step(dt + BK);   // prefetch next tile during MFMA

#pragma unroll
        for (int half = 0; half < 2; ++half) {
            const int dd = half * 32;
            bf16x8 af[2], qf[4];
#pragma unroll
            for (int mt = 0; mt < 2; ++mt) {
                const int r = wm + mt * 16 + lrow;
                const int c = (dd + kg * 8) ^ ((r & 7) << 3);
                af[mt] = *reinterpret_cast<const bf16x8*>(&Al[r * 64 + c]);
            }
#pragma unroll
            for (int nt = 0; nt < 4; ++nt) {
                const int r = wn + nt * 16 + lrow;
                const int c = (dd + kg * 8) ^ ((r & 7) << 3);
                qf[nt] = *reinterpret_cast<const bf16x8*>(&Ql[r * 64 + c]);
            }
#pragma unroll
            for (int mt = 0; mt < 2; ++mt)
#pragma unroll
                for (int nt = 0; nt < 4; ++nt)
                    acc[mt][nt] = __builtin_amdgcn_mfma_f32_16x16x32_bf16(
                        af[mt], qf[nt], acc[mt][nt], 0, 0, 0);
        }
    }

    // ---- epilogue (C/D: col=lane&15 -> b, row=(lane>>4)*4+i -> k) ----
#pragma unroll
    for (int mt = 0; mt < 2; ++mt)
#pragma unroll
        for (int nt = 0; nt < 4; ++nt) {
            const int kk = k0 + wm + mt * 16 + kg * 4;
            const int bb = wn + nt * 16 + lrow;
            if (WSP) {
                *reinterpret_cast<f32x4*>(&outc[((size_t)z * B + bb) * K + kk]) = acc[mt][nt];
            } else {
                float* dst = &outc[(size_t)bb * K + kk];
#pragma unroll
                for (int i = 0; i < 4; ++i) atomicAdd(&dst[i], acc[mt][nt][i]);
            }
        }

    // ---- self partials: reduce 8 threads per row, deterministic store ----
    float s = selfacc;
    s += __shfl_xor(s, 1);
    s += __shfl_xor(s, 2);
    s += __shfl_xor(s, 4);
    if (tq8 == 0) selfp[(size_t)z * K + ar] = s;
}

// ---------------- reduce self partials ----------------
__global__ __launch_bounds__(256)
void selfsum_kernel(const float* __restrict__ selfp, float* __restrict__ selftot, int sch)
{
    const int k = blockIdx.x * 256 + threadIdx.x;
    float s = 0.f;
    for (int z = 0; z < sch; ++z) s += selfp[(size_t)z * K + k];
    selftot[k] = s;
}

// ---------------- per-query top-4 candidates over approx scores ----------------
template<bool WSP>
__global__ __launch_bounds__(256)
void topk_kernel(const float* __restrict__ outc, const float* __restrict__ selftot,
                 int* __restrict__ cand, int sch)
{
    const int b = blockIdx.x, t = threadIdx.x;
    float v[8];
#pragma unroll
    for (int i = 0; i < 8; ++i) {
        const int k = i * 256 + t;
        float cv = 0.f;
        if (WSP) {
            for (int z = 0; z < sch; ++z) cv += outc[((size_t)z * B + b) * K + k];
        } else {
            cv = outc[(size_t)b * K + k];
        }
        v[i] = selftot[k] - cv;
    }
    __shared__ float sv[256];
    __shared__ int   si[256];
    for (int r = 0; r < NC; ++r) {
        float bv = 3.4e38f; int bk = K;
#pragma unroll
        for (int i = 0; i < 8; ++i) {
            const int k = i * 256 + t;
            if (v[i] < bv) { bv = v[i]; bk = k; }
        }
        sv[t] = bv; si[t] = bk;
        __syncthreads();
        for (int off = 128; off > 0; off >>= 1) {
            if (t < off) {
                if (sv[t + off] < sv[t] || (sv[t + off] == sv[t] && si[t + off] < si[t])) {
                    sv[t] = sv[t + off]; si[t] = si[t + off];
                }
            }
            __syncthreads();
        }
        const int kwin = si[0];
        if ((kwin & 255) == t) v[kwin >> 8] = 3.4e38f;
        if (t == 0) cand[b * NC + r] = kwin;
        __syncthreads();
    }
}

// ---------------- exact fp64 rescore of candidates (D split in halves) ----------
__global__ __launch_bounds__(512)
void rescore_kernel(const float* __restrict__ query, const float* __restrict__ anchor,
                    const int* __restrict__ cand, double* __restrict__ pp)
{
    const int b = blockIdx.x, h = blockIdx.y, t = threadIdx.x;
    const int dlo = h * 25129;
    const int dhi = min(D, dlo + 25129);
    int ks[NC];
#pragma unroll
    for (int c = 0; c < NC; ++c) ks[c] = cand[b * NC + c];
    const float* qrow = query + (size_t)b * D;

    double a4[NC];
#pragma unroll
    for (int c = 0; c < NC; ++c) a4[c] = 0.0;

    for (int d = dlo + t; d < dhi; d += 512) {
        const double lqv = (double)logf(qrow[d]);
#pragma unroll
        for (int c = 0; c < NC; ++c)
            a4[c] = fma((double)anchor[(size_t)ks[c] * D + d], lqv, a4[c]);
    }

    __shared__ double red[512];
    for (int c = 0; c < NC; ++c) {
        red[t] = a4[c];
        __syncthreads();
        for (int off = 256; off > 0; off >>= 1) {
            if (t < off) red[t] += red[t + off];
            __syncthreads();
        }
        if (t == 0) pp[((size_t)b * 2 + h) * NC + c] = red[0];
        __syncthreads();
    }
}

// ---------------- final decision + label gather ----------------
__global__ __launch_bounds__(256)
void final_kernel(const double* __restrict__ pp, const float* __restrict__ selftot,
                  const int* __restrict__ cand, const int* __restrict__ label,
                  int* __restrict__ out)
{
    const int b = threadIdx.x;
    float best = 3.4e38f; int bk = K;
#pragma unroll
    for (int c = 0; c < NC; ++c) {
        const int k = cand[b * NC + c];
        const double cv = pp[((size_t)b * 2 + 0) * NC + c] + pp[((size_t)b * 2 + 1) * NC + c];
        const float sc = selftot[k] - (float)cv;
        if (sc < best || (sc == best && k < bk)) { best = sc; bk = k; }
    }
    out[b] = label[bk];
}

extern "C" void kernel_launch(void* const* d_in, const int* in_sizes, int n_in,
                              void* d_out, int out_size, void* d_ws, size_t ws_size,
                              hipStream_t stream)
{
    const float* query  = (const float*)d_in[0];   // [B*D]
    const float* anchor = (const float*)d_in[1];   // [K*D]
    const int*   label  = (const int*)d_in[2];     // [K]
    int* out = (int*)d_out;

    // ---- workspace layout (bytes cursor, aligned) ----
    size_t cur = 0;
    auto alloc = [&](size_t bytes, size_t al) -> void* {
        cur = (cur + al - 1) & ~(al - 1);
        void* p = (char*)d_ws + cur;
        cur += bytes;
        return p;
    };
    unsigned short* lq      = (unsigned short*)alloc((size_t)B * DP * 2, 16);
    float*          selfp   = (float*)alloc((size_t)SCH * K * 4, 16);
    float*          selftot = (float*)alloc((size_t)K * 4, 16);
    int*            cand    = (int*)alloc((size_t)B * NC * 4, 16);
    double*         pp      = (double*)alloc((size_t)B * 2 * NC * 8, 16);
    float*          cross   = (float*)alloc((size_t)B * K * 4, 16);
    float*          part    = (float*)alloc((size_t)SCH * B * K * 4, 16);
    const bool wsp = (cur <= ws_size);

    const int dc = (((D + SCH - 1) / SCH) + BK - 1) / BK * BK;   // 1600
    const int sch_eff = (D + dc - 1) / dc;                        // <= SCH

    lq_kernel<<<1024, 256, 0, stream>>>(query, lq);

    if (wsp) {
        gemm_kernel<true><<<dim3(K / BM, sch_eff), 512, 0, stream>>>(
            anchor, lq, part, selfp, dc);
    } else {
        hipMemsetAsync(cross, 0, (size_t)B * K * sizeof(float), stream);
        gemm_kernel<false><<<dim3(K / BM, sch_eff), 512, 0, stream>>>(
            anchor, lq, cross, selfp, dc);
    }

    selfsum_kernel<<<K / 256, 256, 0, stream>>>(selfp, selftot, sch_eff);

    if (wsp) topk_kernel<true><<<B, 256, 0, stream>>>(part, selftot, cand, sch_eff);
    else     topk_kernel<false><<<B, 256, 0, stream>>>(cross, selftot, cand, sch_eff);

    rescore_kernel<<<dim3(B, 2), 512, 0, stream>>>(query, anchor, cand, pp);
    final_kernel<<<1, 256, 0, stream>>>(pp, selftot, cand, label, out);
}

// Round 4
// 525.054 us; speedup vs baseline: 6.0581x; 1.1216x over previous
//
#include <hip/hip_runtime.h>

// AnchorStore: KL-argmin 1-NN.
//   score[b,k] = sum_d A[k,d]*log A[k,d]  -  sum_d A[k,d]*log Q[b,d]
//   out[b] = label[argmin_k score[b,k]],  K=2048, D=50257, B=256.
// bf16 MFMA GEMM (approx cross) with deterministic per-D-chunk partials,
// exact fp32 self-term, gap-gated fp64 top-8 rescore, label gather.
// sch (# D-chunks) adapts to ws_size; XCD-grouped block swizzle for lq L2 reuse.

constexpr int K   = 2048;
constexpr int D   = 50257;
constexpr int B   = 256;
constexpr int BM  = 64;
constexpr int BK  = 64;
constexpr int DP  = 50320;   // padded log(Q) row stride (mult of 8, >= D+63)
constexpr int NC  = 8;       // rescore candidates
constexpr float MARGIN = 4.0f;   // approx-score gap below which we rescore (~13 sigma)

typedef __attribute__((ext_vector_type(8))) short bf16x8;
typedef __attribute__((ext_vector_type(4))) float f32x4;
typedef __attribute__((ext_vector_type(8))) unsigned short u16x8;

__device__ inline unsigned short f2bf_rne(float f) {
    union { float f; unsigned u; } v; v.f = f;
    unsigned r = v.u + 0x7FFFu + ((v.u >> 16) & 1u);
    return (unsigned short)(r >> 16);
}

// ---------------- pre-pass: lq[b][dp] = bf16(log(q[b][dp])), zero-padded ----
__global__ __launch_bounds__(256)
void lq_kernel(const float* __restrict__ q, unsigned short* __restrict__ lq)
{
    const int stride = gridDim.x * blockDim.x;
    const int total  = B * (DP / 4);
    for (int c = blockIdx.x * blockDim.x + threadIdx.x; c < total; c += stride) {
        const int b   = c / (DP / 4);
        const int off = (c % (DP / 4)) * 4;
        ushort4 w;
        float v0 = (off + 0 < D) ? __logf(q[(size_t)b * D + off + 0]) : 0.f;
        float v1 = (off + 1 < D) ? __logf(q[(size_t)b * D + off + 1]) : 0.f;
        float v2 = (off + 2 < D) ? __logf(q[(size_t)b * D + off + 2]) : 0.f;
        float v3 = (off + 3 < D) ? __logf(q[(size_t)b * D + off + 3]) : 0.f;
        w.x = f2bf_rne(v0); w.y = f2bf_rne(v1); w.z = f2bf_rne(v2); w.w = f2bf_rne(v3);
        *reinterpret_cast<ushort4*>(&lq[(size_t)b * DP + off]) = w;
    }
}

// ---------------- main GEMM: cross[b][k] partials over D-chunks ----------------
// WSP: deterministic part[z][B][K] stores; else atomicAdd into cross[B][K].
// USELQ: read precomputed bf16 log(Q); else compute logf on the fly (tiny-ws fallback).
template<bool WSP, bool USELQ>
__global__ __launch_bounds__(512, 4)
void gemm_kernel(const float* __restrict__ anchor,
                 const float* __restrict__ query,
                 const unsigned short* __restrict__ lq,
                 float* __restrict__ outc,
                 float* __restrict__ selfp,   // [sch][K]
                 int dc, int sch)
{
    // ---- XCD-grouped swizzle: all k-blocks of a z land on few XCDs ----
    const int L   = blockIdx.x;
    const int xcd = L & 7;
    const int j   = L >> 3;
    int x, z;
    if (sch >= 8) { const int zc = sch >> 3; z = xcd * zc + (j >> 5); x = j & 31; }
    else          { const int q8 = 8 / sch;  z = xcd / q8; x = (xcd % q8) * (sch * 4) + j; }

    const int t    = threadIdx.x;
    const int k0   = x * BM;
    const int d0   = z * dc;
    const int dend = min(d0 + dc, D);

    __shared__ __align__(16) unsigned short Al[BM * 64];  //  8 KB, swizzled
    __shared__ __align__(16) unsigned short Ql[B  * 64];  // 32 KB, swizzled

    // A staging: row = t>>3 (0..63), 8 cols at (t&7)*8
    const int rowA = t >> 3;
    const int tq8  = t & 7;
    const int ar   = k0 + rowA;
    const int swA  = (rowA & 7) << 3;
    const float* Arow = anchor + (size_t)ar * D;

    // Q staging: row = t>>1 (0..255), 32 cols at (t&1)*32
    const int rowQ = t >> 1;
    const int hq   = t & 1;
    const int swQ  = (rowQ & 7) << 3;
    const unsigned short* LQrow = lq    + (size_t)rowQ * DP;
    const float*          Qrow  = query + (size_t)rowQ * D;

    // MFMA geometry: 8 waves in 2(m) x 4(n); wave tile 32x64
    const int w    = t >> 6;
    const int lane = t & 63;
    const int wm   = (w >> 2) * 32;
    const int wn   = (w & 3) * 64;
    const int lrow = lane & 15;
    const int kg   = lane >> 4;

    f32x4 acc[2][4];
#pragma unroll
    for (int mt = 0; mt < 2; ++mt)
#pragma unroll
        for (int nt = 0; nt < 4; ++nt)
#pragma unroll
            for (int i = 0; i < 4; ++i) acc[mt][nt][i] = 0.f;

    float selfacc = 0.f;

    float wf[12];
    int   ph = 0;
    u16x8 qreg[4];
    float qf32[32];

    auto load_step = [&](int dt) {
        const int dbase = dt + tq8 * 8;
        if (dbase + 12 <= dend) {
            // vector path: 3 aligned float4 covering [g0-ph, g0-ph+12) ⊇ wanted 8
            const size_t g0 = (size_t)ar * D + dbase;
            ph = (int)(g0 & 3);
            const float4* wp = reinterpret_cast<const float4*>(anchor + (g0 - ph));
            const float4 w0 = wp[0], w1 = wp[1], w2 = wp[2];
            wf[0] = w0.x; wf[1]  = w0.y; wf[2]  = w0.z; wf[3]  = w0.w;
            wf[4] = w1.x; wf[5]  = w1.y; wf[6]  = w1.z; wf[7]  = w1.w;
            wf[8] = w2.x; wf[9]  = w2.y; wf[10] = w2.z; wf[11] = w2.w;
        } else {
            ph = 0;
#pragma unroll
            for (int jj = 0; jj < 8; ++jj) {
                const int d = dbase + jj;
                wf[jj] = (d < dend) ? Arow[d] : 0.f;
            }
#pragma unroll
            for (int jj = 8; jj < 12; ++jj) wf[jj] = 0.f;
        }
        const int qb = dt + hq * 32;
        if constexpr (USELQ) {
#pragma unroll
            for (int g = 0; g < 4; ++g)
                qreg[g] = *reinterpret_cast<const u16x8*>(&LQrow[qb + 8 * g]);
        } else {
#pragma unroll
            for (int jj = 0; jj < 32; ++jj) {
                const int d = qb + jj;
                qf32[jj] = (d < dend) ? Qrow[d] : 1.f;   // log(1)=0
            }
        }
    };

    load_step(d0);

    for (int dt = d0; dt < dend; dt += BK) {
        // ---- alignment-phase select (compile-time indices only) ----
        float s1[9], av[8];
#pragma unroll
        for (int jj = 0; jj < 9; ++jj) s1[jj] = (ph & 2) ? wf[jj + 2] : wf[jj];
#pragma unroll
        for (int jj = 0; jj < 8; ++jj) av[jj] = (ph & 1) ? s1[jj + 1] : s1[jj];

        unsigned short abf[8];
#pragma unroll
        for (int jj = 0; jj < 8; ++jj) {
            if (av[jj] > 0.f) selfacc = fmaf(av[jj], __logf(av[jj]), selfacc);
            abf[jj] = f2bf_rne(av[jj]);
        }
        u16x8 qb4[4];
        if constexpr (USELQ) {
#pragma unroll
            for (int g = 0; g < 4; ++g) qb4[g] = qreg[g];
        } else {
#pragma unroll
            for (int g = 0; g < 4; ++g)
#pragma unroll
                for (int jj = 0; jj < 8; ++jj)
                    qb4[g][jj] = f2bf_rne(__logf(qf32[g * 8 + jj]));
        }

        __syncthreads();   // previous step's MFMA readers done
        {
            unsigned short* a0 = &Al[rowA * 64 + ((tq8 * 8) ^ swA)];
            reinterpret_cast<ushort4*>(a0)[0] = ushort4{abf[0], abf[1], abf[2], abf[3]};
            reinterpret_cast<ushort4*>(a0)[1] = ushort4{abf[4], abf[5], abf[6], abf[7]};
#pragma unroll
            for (int g = 0; g < 4; ++g)
                *reinterpret_cast<u16x8*>(&Ql[rowQ * 64 + ((hq * 32 + 8 * g) ^ swQ)]) = qb4[g];
        }
        __syncthreads();

        if (dt + BK < dend) load_step(dt + BK);   // prefetch next tile during MFMA

#pragma unroll
        for (int half = 0; half < 2; ++half) {
            const int dd = half * 32;
            bf16x8 af[2], qf[4];
#pragma unroll
            for (int mt = 0; mt < 2; ++mt) {
                const int r = wm + mt * 16 + lrow;
                const int c = (dd + kg * 8) ^ ((r & 7) << 3);
                af[mt] = *reinterpret_cast<const bf16x8*>(&Al[r * 64 + c]);
            }
#pragma unroll
            for (int nt = 0; nt < 4; ++nt) {
                const int r = wn + nt * 16 + lrow;
                const int c = (dd + kg * 8) ^ ((r & 7) << 3);
                qf[nt] = *reinterpret_cast<const bf16x8*>(&Ql[r * 64 + c]);
            }
#pragma unroll
            for (int mt = 0; mt < 2; ++mt)
#pragma unroll
                for (int nt = 0; nt < 4; ++nt)
                    acc[mt][nt] = __builtin_amdgcn_mfma_f32_16x16x32_bf16(
                        af[mt], qf[nt], acc[mt][nt], 0, 0, 0);
        }
    }

    // ---- epilogue (C/D: col=lane&15 -> b, row=(lane>>4)*4+i -> k) ----
#pragma unroll
    for (int mt = 0; mt < 2; ++mt)
#pragma unroll
        for (int nt = 0; nt < 4; ++nt) {
            const int kk = k0 + wm + mt * 16 + kg * 4;
            const int bb = wn + nt * 16 + lrow;
            if (WSP) {
                *reinterpret_cast<f32x4*>(&outc[((size_t)z * B + bb) * K + kk]) = acc[mt][nt];
            } else {
                float* dst = &outc[(size_t)bb * K + kk];
#pragma unroll
                for (int i = 0; i < 4; ++i) atomicAdd(&dst[i], acc[mt][nt][i]);
            }
        }

    // ---- self partials: reduce 8 threads per row, deterministic store ----
    float s = selfacc;
    s += __shfl_xor(s, 1);
    s += __shfl_xor(s, 2);
    s += __shfl_xor(s, 4);
    if (tq8 == 0) selfp[(size_t)z * K + ar] = s;
}

// ---------------- reduce self partials ----------------
__global__ __launch_bounds__(256)
void selfsum_kernel(const float* __restrict__ selfp, float* __restrict__ selftot, int sch)
{
    const int k = blockIdx.x * 256 + threadIdx.x;
    float s = 0.f;
    for (int z = 0; z < sch; ++z) s += selfp[(size_t)z * K + k];
    selftot[k] = s;
}

// ---------------- per-query top-NC candidates + rescore-need gap flag ----------
template<bool WSP>
__global__ __launch_bounds__(256)
void topk_kernel(const float* __restrict__ outc, const float* __restrict__ selftot,
                 int* __restrict__ cand, int* __restrict__ need, int sch)
{
    const int b = blockIdx.x, t = threadIdx.x;
    float v[8];
#pragma unroll
    for (int i = 0; i < 8; ++i) {
        const int k = i * 256 + t;
        float cv = 0.f;
        if (WSP) {
            for (int z = 0; z < sch; ++z) cv += outc[((size_t)z * B + b) * K + k];
        } else {
            cv = outc[(size_t)b * K + k];
        }
        v[i] = selftot[k] - cv;
    }
    __shared__ float sv[256];
    __shared__ int   si[256];
    __shared__ float topv[2];
    for (int r = 0; r < NC; ++r) {
        float bv = 3.4e38f; int bk = K;
#pragma unroll
        for (int i = 0; i < 8; ++i) {
            const int k = i * 256 + t;
            if (v[i] < bv) { bv = v[i]; bk = k; }
        }
        sv[t] = bv; si[t] = bk;
        __syncthreads();
        for (int off = 128; off > 0; off >>= 1) {
            if (t < off) {
                if (sv[t + off] < sv[t] || (sv[t + off] == sv[t] && si[t + off] < si[t])) {
                    sv[t] = sv[t + off]; si[t] = si[t + off];
                }
            }
            __syncthreads();
        }
        const int kwin = si[0];
        if ((kwin & 255) == t) v[kwin >> 8] = 3.4e38f;
        if (t == 0) {
            cand[b * NC + r] = kwin;
            if (r < 2) topv[r] = sv[0];
        }
        __syncthreads();
    }
    if (t == 0) need[b] = (topv[1] - topv[0] < MARGIN) ? 1 : 0;
}

// ---------------- exact fp64 rescore of flagged queries (D split in halves) ----
__global__ __launch_bounds__(512)
void rescore_kernel(const float* __restrict__ query, const float* __restrict__ anchor,
                    const int* __restrict__ cand, const int* __restrict__ need,
                    double* __restrict__ pp)
{
    const int b = blockIdx.x, h = blockIdx.y, t = threadIdx.x;
    if (!need[b]) return;   // gap certain: skip (all threads exit before any barrier)
    const int dlo = h * 25129;
    const int dhi = min(D, dlo + 25129);
    int ks[NC];
#pragma unroll
    for (int c = 0; c < NC; ++c) ks[c] = cand[b * NC + c];
    const float* qrow = query + (size_t)b * D;

    double a8[NC];
#pragma unroll
    for (int c = 0; c < NC; ++c) a8[c] = 0.0;

    for (int d = dlo + t; d < dhi; d += 512) {
        const double lqv = (double)logf(qrow[d]);
#pragma unroll
        for (int c = 0; c < NC; ++c)
            a8[c] = fma((double)anchor[(size_t)ks[c] * D + d], lqv, a8[c]);
    }

    __shared__ double red[512];
    for (int c = 0; c < NC; ++c) {
        red[t] = a8[c];
        __syncthreads();
        for (int off = 256; off > 0; off >>= 1) {
            if (t < off) red[t] += red[t + off];
            __syncthreads();
        }
        if (t == 0) pp[((size_t)b * 2 + h) * NC + c] = red[0];
        __syncthreads();
    }
}

// ---------------- final decision + label gather ----------------
__global__ __launch_bounds__(256)
void final_kernel(const double* __restrict__ pp, const float* __restrict__ selftot,
                  const int* __restrict__ cand, const int* __restrict__ need,
                  const int* __restrict__ label, int* __restrict__ out)
{
    const int b = threadIdx.x;
    if (!need[b]) { out[b] = label[cand[b * NC]]; return; }
    float best = 3.4e38f; int bk = K;
#pragma unroll
    for (int c = 0; c < NC; ++c) {
        const int k = cand[b * NC + c];
        const double cv = pp[((size_t)b * 2 + 0) * NC + c] + pp[((size_t)b * 2 + 1) * NC + c];
        const float sc = selftot[k] - (float)cv;
        if (sc < best || (sc == best && k < bk)) { best = sc; bk = k; }
    }
    out[b] = label[bk];
}

extern "C" void kernel_launch(void* const* d_in, const int* in_sizes, int n_in,
                              void* d_out, int out_size, void* d_ws, size_t ws_size,
                              hipStream_t stream)
{
    const float* query  = (const float*)d_in[0];   // [B*D]
    const float* anchor = (const float*)d_in[1];   // [K*D]
    const int*   label  = (const int*)d_in[2];     // [K]
    int* out = (int*)d_out;

    size_t cur = 0;
    auto alloc = [&](size_t bytes) -> void* {
        cur = (cur + 255) & ~(size_t)255;
        void* p = (char*)d_ws + cur;
        cur += bytes;
        return p;
    };

    unsigned short* lq      = (unsigned short*)alloc((size_t)B * DP * 2);  // 25.8 MB
    float*          selfp   = (float*)alloc((size_t)16 * K * 4);
    float*          selftot = (float*)alloc((size_t)K * 4);
    int*            cand    = (int*)alloc((size_t)B * NC * 4);
    int*            need    = (int*)alloc((size_t)B * 4);
    double*         pp      = (double*)alloc((size_t)B * 2 * NC * 8);
    const size_t fixed_end  = cur;

    // largest power-of-2 chunk count whose partials fit the remaining ws
    int sch = 0;
    for (int s = 16; s >= 2; s >>= 1)
        if (fixed_end + (size_t)s * B * K * 4 + 256 <= ws_size) { sch = s; break; }

    if (sch) {
        // ---- deterministic-partials path ----
        float* part = (float*)alloc((size_t)sch * B * K * 4);
        const int dc = (((D + sch - 1) / sch) + BK - 1) / BK * BK;
        lq_kernel<<<1024, 256, 0, stream>>>(query, lq);
        gemm_kernel<true, true><<<32 * sch, 512, 0, stream>>>(
            anchor, query, lq, part, selfp, dc, sch);
        selfsum_kernel<<<K / 256, 256, 0, stream>>>(selfp, selftot, sch);
        topk_kernel<true><<<B, 256, 0, stream>>>(part, selftot, cand, need, sch);
    } else if (fixed_end + (size_t)B * K * 4 + 256 <= ws_size) {
        // ---- atomic fallback, lq precomputed ----
        float* cross = (float*)alloc((size_t)B * K * 4);
        const int s8 = 8;
        const int dc = (((D + s8 - 1) / s8) + BK - 1) / BK * BK;
        hipMemsetAsync(cross, 0, (size_t)B * K * sizeof(float), stream);
        lq_kernel<<<1024, 256, 0, stream>>>(query, lq);
        gemm_kernel<false, true><<<32 * s8, 512, 0, stream>>>(
            anchor, query, lq, cross, selfp, dc, s8);
        selfsum_kernel<<<K / 256, 256, 0, stream>>>(selfp, selftot, s8);
        topk_kernel<false><<<B, 256, 0, stream>>>(cross, selftot, cand, need, s8);
    } else {
        // ---- minimal-ws fallback: no lq, on-the-fly logf, atomics ----
        cur = 0;
        float* cross = (float*)alloc((size_t)B * K * 4);
        selfp   = (float*)alloc((size_t)16 * K * 4);
        selftot = (float*)alloc((size_t)K * 4);
        cand    = (int*)alloc((size_t)B * NC * 4);
        need    = (int*)alloc((size_t)B * 4);
        pp      = (double*)alloc((size_t)B * 2 * NC * 8);
        const int s8 = 8;
        const int dc = (((D + s8 - 1) / s8) + BK - 1) / BK * BK;
        hipMemsetAsync(cross, 0, (size_t)B * K * sizeof(float), stream);
        gemm_kernel<false, false><<<32 * s8, 512, 0, stream>>>(
            anchor, query, lq, cross, selfp, dc, s8);
        selfsum_kernel<<<K / 256, 256, 0, stream>>>(selfp, selftot, s8);
        topk_kernel<false><<<B, 256, 0, stream>>>(cross, selftot, cand, need, s8);
    }

    rescore_kernel<<<dim3(B, 2), 512, 0, stream>>>(query, anchor, cand, need, pp);
    final_kernel<<<1, 256, 0, stream>>>(pp, selftot, cand, need, label, out);
}